// Round 7
// baseline (457.712 us; speedup 1.0000x reference)
//
#include <hip/hip_runtime.h>

// WindowMultiHeadAttention: b=4, n=4096, d=1024, H=16, dk=64, WIN=64, nw=64.
// R7: two changes vs R6 (GEMM core + attn remain R0-verbatim):
//  1. cvt3 -> G11 grid-stride form: 2048 blocks, 12 chunks/thread (was 24576
//     one-shot blocks at ~2.5 TB/s inferred). Target ~5 TB/s.
//  2. ZERO writes to input buffers (R0..R6 wrote Wb/Xv into d_in; the harness
//     restores dirtied inputs inside the timed region -> suspected ~70us).
//     All scratch lives in ws (100.66MB proven) + d_out (64MB):
//
//       step                     ws0        ws1        ws2        do0   do1
//       cvt3s  q,k,v->bf16       qb W       kb W       vb W       -     -
//       cvtw3  Wq/Wk/Wv->bf16    -          -          -          -     W(6.3M)
//       gemm_q Xq=qb*Wq'         qb R                             Xq W  R
//       gemm_k Xk=kb*Wk'         Xk W       kb R                        R
//       gemm_v Xv=vb*Wv'                    Xv W       vb R             R
//       attn                     Xk R       Xv R       Xo W       Xq R
//       cvtwo  Wo->bf16          Wo16 W(2M)
//       gemm_o C=Xo*Wo'          Wo16 R                Xo R       C(fp32, 64M)
//
//     Every cell written only after its previous tenant is consumed;
//     gemm_o reads ws only, writes d_out only. Inputs are read-only.

typedef unsigned short u16;
typedef unsigned int u32;
typedef __bf16 bf16x8 __attribute__((ext_vector_type(8)));
typedef float f32x4 __attribute__((ext_vector_type(4)));
typedef u16 u16x8 __attribute__((ext_vector_type(8)));

__device__ __forceinline__ u16 f2bf(float f) {
  u32 u = __builtin_bit_cast(u32, f);
  u += 0x7fffu + ((u >> 16) & 1u);  // RNE
  return (u16)(u >> 16);
}

__device__ __forceinline__ void cvt8_store(const float* __restrict__ src,
                                           u16* __restrict__ dst, size_t i) {
  const float4 a = *(const float4*)(src + i);
  const float4 b = *(const float4*)(src + i + 4);
  u16x8 r;
  r[0] = f2bf(a.x); r[1] = f2bf(a.y); r[2] = f2bf(a.z); r[3] = f2bf(a.w);
  r[4] = f2bf(b.x); r[5] = f2bf(b.y); r[6] = f2bf(b.z); r[7] = f2bf(b.w);
  *(u16x8*)(dst + i) = r;
}

// q,k,v (16.78M elems each) -> bf16 into ws slots. G11: 2048 blocks,
// grid-stride; 3 tensors x 4 strided chunks of 8 elems per thread (all 12
// load-pairs independent -> deep MLP).
__global__ __launch_bounds__(256) void cvt3s_kernel(
    const float* __restrict__ q, const float* __restrict__ k,
    const float* __restrict__ v, u16* __restrict__ ws) {
  const int g = blockIdx.x * 256 + threadIdx.x;  // 0..524287
#pragma unroll
  for (int z = 0; z < 3; ++z) {
    const float* src = (z == 0) ? q : (z == 1) ? k : v;
    u16* dst = ws + (size_t)z * 16777216;
#pragma unroll
    for (int i = 0; i < 4; ++i)
      cvt8_store(src, dst, ((size_t)g + (size_t)i * 524288) * 8);
  }
}

// Wq/Wk/Wv fp32 -> bf16 (1M elems each), z selects.
__global__ __launch_bounds__(256) void cvtw3_kernel(
    const float* __restrict__ Wq, const float* __restrict__ Wk,
    const float* __restrict__ Wv, u16* __restrict__ dst) {
  const float* src = (blockIdx.z == 0) ? Wq : (blockIdx.z == 1) ? Wk : Wv;
  cvt8_store(src, dst + (size_t)blockIdx.z * 1048576,
             ((size_t)blockIdx.x * 256 + threadIdx.x) * 8);
}

// Wo fp32 -> bf16 (1M elems).
__global__ __launch_bounds__(256) void cvtwo_kernel(
    const float* __restrict__ Wo, u16* __restrict__ dst) {
  cvt8_store(Wo, dst, ((size_t)blockIdx.x * 256 + threadIdx.x) * 8);
}

__device__ __forceinline__ void cp16(const u16* g, u16* l) {
  // async global->LDS, 16B/lane; LDS dst = wave-uniform base + lane*16.
  __builtin_amdgcn_global_load_lds((const __attribute__((address_space(1))) void*)g,
                                   (__attribute__((address_space(3))) void*)l, 16, 0, 0);
}

// C[M,N] = A[M,K]*B[N,K]^T, bf16 in, fp32 acc. M=16384, N=K=1024.
// 128x128 tile, BK=32, 4 waves 2x2, 1024 blocks. XCD-aware swizzle:
// XCD x owns m-tiles [x*16,x*16+16), n fastest (R0-proven: 48.5us).
__device__ __forceinline__ void gemm_core(const u16* __restrict__ A,
                                          const u16* __restrict__ B,
                                          void* __restrict__ Cv, int cf) {
  constexpr int N = 1024, K = 1024;
  __shared__ u16 lA[128 * 32];
  __shared__ u16 lB[128 * 32];
  const int tid = threadIdx.x;
  const int lane = tid & 63, w = tid >> 6;
  const int quad = lane >> 4, lr = lane & 15;
  const int lid = blockIdx.x;
  const int xcd = lid & 7, slot = lid >> 3;
  const int m0 = (xcd * 16 + (slot >> 3)) * 128;
  const int n0 = (slot & 7) * 128;
  const int wr = (w >> 1) * 64, wc = (w & 1) * 64;

  const int ch1 = tid, ch2 = tid + 256;  // 512 x 16B chunks per 128x32 tile
  const u16* Ag1 = A + (size_t)(m0 + (ch1 >> 2)) * K + (ch1 & 3) * 8;
  const u16* Ag2 = A + (size_t)(m0 + (ch2 >> 2)) * K + (ch2 & 3) * 8;
  const u16* Bg1 = B + (size_t)(n0 + (ch1 >> 2)) * K + (ch1 & 3) * 8;
  const u16* Bg2 = B + (size_t)(n0 + (ch2 >> 2)) * K + (ch2 & 3) * 8;

  f32x4 acc[4][4] = {};
  for (int k0 = 0; k0 < K; k0 += 32) {
    cp16(Ag1 + k0, &lA[ch1 * 8]);
    cp16(Ag2 + k0, &lA[ch2 * 8]);
    cp16(Bg1 + k0, &lB[ch1 * 8]);
    cp16(Bg2 + k0, &lB[ch2 * 8]);
    __syncthreads();  // drains vmcnt(0): staged data visible
    bf16x8 afr[4], bfr[4];
#pragma unroll
    for (int mi = 0; mi < 4; ++mi)
      afr[mi] = *(const bf16x8*)&lA[(wr + mi * 16 + lr) * 32 + quad * 8];
#pragma unroll
    for (int ni = 0; ni < 4; ++ni)
      bfr[ni] = *(const bf16x8*)&lB[(wc + ni * 16 + lr) * 32 + quad * 8];
#pragma unroll
    for (int mi = 0; mi < 4; ++mi)
#pragma unroll
      for (int ni = 0; ni < 4; ++ni)
        acc[mi][ni] = __builtin_amdgcn_mfma_f32_16x16x32_bf16(afr[mi], bfr[ni], acc[mi][ni], 0, 0, 0);
    __syncthreads();
  }
  // C/D layout per 16x16 tile: row = quad*4+r, col = lr
#pragma unroll
  for (int mi = 0; mi < 4; ++mi)
#pragma unroll
    for (int r = 0; r < 4; ++r) {
      const int row = m0 + wr + mi * 16 + quad * 4 + r;
      if (!cf) {
        u16* dst = (u16*)Cv + (size_t)row * N + n0 + wc + lr;
#pragma unroll
        for (int ni = 0; ni < 4; ++ni) dst[ni * 16] = f2bf(acc[mi][ni][r]);
      } else {
        float* dst = (float*)Cv + (size_t)row * N + n0 + wc + lr;
#pragma unroll
        for (int ni = 0; ni < 4; ++ni) dst[ni * 16] = acc[mi][ni][r];
      }
    }
}

__global__ __launch_bounds__(256, 2) void gemm_bf_kernel(
    const u16* __restrict__ A, const u16* __restrict__ B,
    u16* __restrict__ C) {
  gemm_core(A, B, C, 0);
}

__global__ __launch_bounds__(256, 2) void gemm_of_kernel(
    const u16* __restrict__ A, const u16* __restrict__ B,
    float* __restrict__ C) {
  gemm_core(A, B, C, 1);
}

// One wave per (b, h, window). 64q x 64k x dk=64, bf16. LDS = P only (9.2 KB).
__global__ __launch_bounds__(64) void attn_win_kernel(
    const u16* __restrict__ Xq, const u16* __restrict__ Xk, const u16* __restrict__ Xv,
    u16* __restrict__ Xo) {
  __shared__ u16 P[64 * 72];  // [qp][kp], stride 72 keeps 16B row alignment
  const int bx = blockIdx.x;  // 0..4095
  const int wi = bx & 63, h = (bx >> 6) & 15, b = bx >> 10;
  const int lane = threadIdx.x & 63, quad = lane >> 4, lr = lane & 15;
  const size_t tb = (size_t)b * 4096 + wi * 64;  // window = 64 contiguous tokens
  const u16* qb = Xq + tb * 1024 + h * 64;
  const u16* kb = Xk + tb * 1024 + h * 64;
  const u16* vb = Xv + tb * 1024 + h * 64;

  // S = Q K^T: A-frag Q[m=lr+16mi][k=quad*8+j+32ks]; B-frag K[n=lr+16ni][k]
  bf16x8 aq[4][2], bk[4][2];
#pragma unroll
  for (int mi = 0; mi < 4; ++mi)
#pragma unroll
    for (int ks = 0; ks < 2; ++ks) {
      aq[mi][ks] = *(const bf16x8*)(qb + (size_t)(mi * 16 + lr) * 1024 + ks * 32 + quad * 8);
      bk[mi][ks] = *(const bf16x8*)(kb + (size_t)(mi * 16 + lr) * 1024 + ks * 32 + quad * 8);
    }
  f32x4 s[4][4];
#pragma unroll
  for (int mi = 0; mi < 4; ++mi)
#pragma unroll
    for (int ni = 0; ni < 4; ++ni) {
      f32x4 z = {0.f, 0.f, 0.f, 0.f};
      z = __builtin_amdgcn_mfma_f32_16x16x32_bf16(aq[mi][0], bk[ni][0], z, 0, 0, 0);
      s[mi][ni] = __builtin_amdgcn_mfma_f32_16x16x32_bf16(aq[mi][1], bk[ni][1], z, 0, 0, 0);
    }

  // V B-frags from global, overlapping the softmax latency:
  u16x8 bvr[2][4];
#pragma unroll
  for (int ks = 0; ks < 2; ++ks)
#pragma unroll
    for (int ci = 0; ci < 4; ++ci) {
      const u16* vc = vb + (size_t)(ks * 32 + quad * 8) * 1024 + ci * 16 + lr;
#pragma unroll
      for (int j = 0; j < 8; ++j) bvr[ks][ci][j] = vc[(size_t)j * 1024];
    }

  // softmax: row (quad*4+r of tile mi) spans this quad's 16 lanes x 4 ni regs
  const float sc = 0.125f;  // 1/sqrt(64)
#pragma unroll
  for (int mi = 0; mi < 4; ++mi)
#pragma unroll
    for (int r = 0; r < 4; ++r) {
      float mx = fmaxf(fmaxf(s[mi][0][r], s[mi][1][r]), fmaxf(s[mi][2][r], s[mi][3][r]));
#pragma unroll
      for (int m = 1; m < 16; m <<= 1) mx = fmaxf(mx, __shfl_xor(mx, m));
      float sum = 0.f;
#pragma unroll
      for (int ni = 0; ni < 4; ++ni) {
        float p = __expf((s[mi][ni][r] - mx) * sc);
        s[mi][ni][r] = p;
        sum += p;
      }
#pragma unroll
      for (int m = 1; m < 16; m <<= 1) sum += __shfl_xor(sum, m);
      const float inv = 1.f / sum;
#pragma unroll
      for (int ni = 0; ni < 4; ++ni) s[mi][ni][r] *= inv;
    }

  // P (C/D layout) -> LDS row-major
#pragma unroll
  for (int mi = 0; mi < 4; ++mi)
#pragma unroll
    for (int ni = 0; ni < 4; ++ni)
#pragma unroll
      for (int r = 0; r < 4; ++r)
        P[(mi * 16 + quad * 4 + r) * 72 + ni * 16 + lr] = f2bf(s[mi][ni][r]);
  __syncthreads();  // single wave: compiles to lgkmcnt drain

  // O = P V
  f32x4 o[4][4] = {};
#pragma unroll
  for (int ks = 0; ks < 2; ++ks) {
    bf16x8 ap[4];
#pragma unroll
    for (int mi = 0; mi < 4; ++mi)
      ap[mi] = *(const bf16x8*)&P[(mi * 16 + lr) * 72 + ks * 32 + quad * 8];
#pragma unroll
    for (int mi = 0; mi < 4; ++mi)
#pragma unroll
      for (int ci = 0; ci < 4; ++ci)
        o[mi][ci] = __builtin_amdgcn_mfma_f32_16x16x32_bf16(
            ap[mi], __builtin_bit_cast(bf16x8, bvr[ks][ci]), o[mi][ci], 0, 0, 0);
  }

  // reference permutation: out token = qp*64 + wi
#pragma unroll
  for (int mi = 0; mi < 4; ++mi)
#pragma unroll
    for (int r = 0; r < 4; ++r) {
      const int qp = mi * 16 + quad * 4 + r;
      u16* dst = Xo + ((size_t)b * 4096 + (size_t)qp * 64 + wi) * 1024 + h * 64 + lr;
#pragma unroll
      for (int ci = 0; ci < 4; ++ci) dst[ci * 16] = f2bf(o[mi][ci][r]);
    }
}

extern "C" void kernel_launch(void* const* d_in, const int* in_sizes, int n_in,
                              void* d_out, int out_size, void* d_ws, size_t ws_size,
                              hipStream_t stream) {
  (void)in_sizes; (void)n_in; (void)out_size; (void)ws_size;
  const float* q  = (const float*)d_in[0];
  const float* k  = (const float*)d_in[1];
  const float* v  = (const float*)d_in[2];
  const float* Wq = (const float*)d_in[3];
  const float* Wk = (const float*)d_in[4];
  const float* Wv = (const float*)d_in[5];
  const float* Wo = (const float*)d_in[6];

  constexpr size_t ELEMS = (size_t)16384 * 1024;
  u16* ws0 = (u16*)d_ws;               // qb -> Xk -> Wo16
  u16* ws1 = ws0 + ELEMS;              // kb -> Xv
  u16* ws2 = ws1 + ELEMS;              // vb -> Xo
  u16* do0 = (u16*)d_out;              // Xq (bf16) -> final fp32 C (lower)
  u16* do1 = do0 + ELEMS;              // Wq/Wk/Wv bf16 (6.3MB) -> final C (upper)

  cvt3s_kernel<<<2048, 256, 0, stream>>>(q, k, v, ws0);
  cvtw3_kernel<<<dim3(512, 1, 3), 256, 0, stream>>>(Wq, Wk, Wv, do1);
  gemm_bf_kernel<<<1024, 256, 0, stream>>>(ws0, do1,           do0);  // Xq
  gemm_bf_kernel<<<1024, 256, 0, stream>>>(ws1, do1 + 1048576, ws0);  // Xk
  gemm_bf_kernel<<<1024, 256, 0, stream>>>(ws2, do1 + 2097152, ws1);  // Xv
  attn_win_kernel<<<dim3(4096), 64, 0, stream>>>(do0, ws0, ws1, ws2);
  cvtwo_kernel<<<512, 256, 0, stream>>>(Wo, ws0);
  gemm_of_kernel<<<1024, 256, 0, stream>>>(ws2, ws0, (float*)d_out);
}